// Round 7
// baseline (99.359 us; speedup 1.0000x reference)
//
#include <hip/hip_runtime.h>
#include <hip/hip_bf16.h>
#include <cstdint>

// Conv2d 3x3 s1 p1, NCHW fp32 -> implicit GEMM on bf16 MFMA.
// x: [32][128][56][56] f32, filters: [256][128][3][3] f32, biases: [256] f32
// out: [32][256][56][56] f32
// ws: Xp (NHWC padded bf16 [32][58][58][128]) then Wt (bf16 [9][256][128]).
//
// R7: 256(M)x256(N) tile, 512 thr / 8 waves (2M x 4N), per-wave 128x64.
// BK=32 -> 36 K-tiles, 2 phases each (16 MFMA/phase). Ring-3 LDS bufs of
// 32KB (A 16K | B 16K) = 96KB. Prefetch distance 2 (stage tile t+2 during
// tile t, 2 gload_lds per phase), ONE counted vmcnt(4) per tile bottom ->
// every staging load gets ~3-4 phases of latency cover.

typedef __bf16 bf16x8 __attribute__((ext_vector_type(8)));
typedef float f32x4 __attribute__((ext_vector_type(4)));

#define XP_ELEMS (32 * 430592)            // 58*58*128 per image
#define XP_BYTES (XP_ELEMS * 2)           // 27,557,888
#define WT_ELEMS (9 * 256 * 128)          // 294,912

__device__ __forceinline__ unsigned short f2bf(float f) {
  __bf16 b = (__bf16)f;
  return __builtin_bit_cast(unsigned short, b);
}

__device__ __forceinline__ void gload16(const void* g, void* l) {
  __builtin_amdgcn_global_load_lds(
      (const __attribute__((address_space(1))) unsigned int*)g,
      (__attribute__((address_space(3))) unsigned int*)l,
      16, 0, 0);
}

// ---- prep: x NCHW f32 -> padded NHWC bf16 ------------------------------
__global__ __launch_bounds__(256) void prep_x(const float* __restrict__ x,
                                              unsigned short* __restrict__ xp) {
  __shared__ unsigned short lt[64][34];  // [hw][c] tile, padded stride
  int b = blockIdx.x;
  int hwt = b % 49;          // 49 tiles of 64 hw positions
  int ct  = (b / 49) & 3;    // 4 tiles of 32 channels
  int n   = b / 196;
  int t = threadIdx.x;
  int c_loc = t >> 3, col8 = t & 7;
  int hw0 = hwt << 6, c0 = ct << 5;

  const float* src = x + ((n * 128 + c0 + c_loc) * 3136 + hw0 + (col8 << 3));
  float4 v0 = *(const float4*)src;
  float4 v1 = *(const float4*)(src + 4);
  int hb = col8 << 3;
  lt[hb + 0][c_loc] = f2bf(v0.x);
  lt[hb + 1][c_loc] = f2bf(v0.y);
  lt[hb + 2][c_loc] = f2bf(v0.z);
  lt[hb + 3][c_loc] = f2bf(v0.w);
  lt[hb + 4][c_loc] = f2bf(v1.x);
  lt[hb + 5][c_loc] = f2bf(v1.y);
  lt[hb + 6][c_loc] = f2bf(v1.z);
  lt[hb + 7][c_loc] = f2bf(v1.w);
  __syncthreads();

  int hwl = t >> 2, cs = t & 3;
  const unsigned int* lr = (const unsigned int*)&lt[hwl][cs << 3];
  uint4 o = make_uint4(lr[0], lr[1], lr[2], lr[3]);
  int hw = hw0 + hwl;
  int hp = hw / 56 + 1, wp = hw % 56 + 1;
  unsigned short* dst = xp + (n * 430592 + (hp * 58 + wp) * 128 + c0 + (cs << 3));
  *(uint4*)dst = o;
}

// ---- prep: zero the padding border of Xp -------------------------------
__global__ __launch_bounds__(256) void border_zero(unsigned short* __restrict__ xp) {
  int idx = blockIdx.x * 256 + threadIdx.x;   // grid sized exactly 116736
  int img = idx / 3648;
  int j = idx - img * 3648;
  int u4off;
  if (j < 928) {
    u4off = j;                      // row hp=0
  } else if (j < 1856) {
    u4off = 52896 + (j - 928);      // row hp=57
  } else {
    int k = j - 1856;
    int hp = 1 + (k >> 5);
    int r = k & 31;
    int wp = (r < 16) ? 0 : 57;
    u4off = (hp * 58 + wp) * 16 + (r & 15);
  }
  uint4 z = make_uint4(0u, 0u, 0u, 0u);
  *((uint4*)xp + img * 53824 + u4off) = z;
}

// ---- prep: filters OIHW f32 -> Wt[9][256][128] bf16 --------------------
__global__ __launch_bounds__(256) void prep_w(const float* __restrict__ f,
                                              unsigned short* __restrict__ wt) {
  int idx = blockIdx.x * 256 + threadIdx.x;  // < 294912
  int c = idx & 127;
  int k = (idx >> 7) & 255;
  int rs = idx >> 15;
  wt[idx] = f2bf(f[(k * 128 + c) * 9 + rs]);
}

// ---- main: implicit GEMM, 256x256, ring-3, 2-phase K-tiles -------------
#define MF(A, B, C) __builtin_amdgcn_mfma_f32_16x16x32_bf16((A), (B), (C), 0, 0, 0)

__global__ __launch_bounds__(512, 2) void conv_mfma(const unsigned short* __restrict__ xp,
                                                    const unsigned short* __restrict__ wt,
                                                    const float* __restrict__ bias,
                                                    float* __restrict__ out) {
  __shared__ unsigned short lds[49152];  // 96KB: 3 bufs x (A 16K | B 16K)
  char* ldsc = (char*)lds;
  int bid = blockIdx.x;
  int pt = (bid & 7) * 49 + (bid >> 3);   // 392 = 8*49 XCD-bijective
  int t = threadIdx.x;
  int wv = t >> 6, l = t & 63;
  int wr = wv >> 2, wc = wv & 3;          // 2M x 4N waves
  int r15 = l & 15, hi = l >> 4;

  // staging map: row = t>>2 (0..127), phys 16B slot = t&3.
  // LDS[row][phys] holds data slot phys^f(row), f(row)=(row>>1)&3.
  int row0 = t >> 2;
  int sd = (t & 3) ^ ((t >> 3) & 3);
  const unsigned short* srcA = wt + row0 * 128 + sd * 8;     // +j*16384 +oA
  const unsigned short* srcB0;
  const unsigned short* srcB1;
  {
    const unsigned short* sb[2];
#pragma unroll
    for (int j = 0; j < 2; ++j) {
      int p = (pt << 8) + (j << 7) + row0;
      int ni = p / 3136, hw = p - ni * 3136;
      sb[j] = xp + (ni * 430592 + ((hw / 56) * 58 + (hw % 56)) * 128 + sd * 8);
    }
    srcB0 = sb[0]; srcB1 = sb[1];
  }
  int stW = wv << 10;  // wave's 1KB chunk per 8KB region (16 rows x 64B)

#define GA(j, oA, bufb) gload16(srcA + ((j) << 14) + (oA), ldsc + (bufb) + ((j) << 13) + stW)
#define GB0(oB, bufb) gload16(srcB0 + (oB), ldsc + (bufb) + 16384 + stW)
#define GB1(oB, bufb) gload16(srcB1 + (oB), ldsc + (bufb) + 16384 + 8192 + stW)

  // fragment read offsets: data slot hi of row r -> phys hi^((r15>>1)&3)
  int xr = (r15 >> 1) & 3;
  int laneA = ((wr << 7) + r15) * 64 + ((hi ^ xr) << 4);            // + m*1024
  int laneB = 16384 + ((wc << 6) + r15) * 64 + ((hi ^ xr) << 4);    // + n*1024

  f32x4 acc[8][4];
#pragma unroll
  for (int m = 0; m < 8; ++m)
#pragma unroll
    for (int n = 0; n < 4; ++n) acc[m][n] = (f32x4){0.f, 0.f, 0.f, 0.f};

  // tile q: tap = q>>2, ct = q&3; oA = tap*32768 + ct*32,
  // oB = ((tap/3)*58 + tap%3)*128 + ct*32.
  // prologue: tile0 -> buf0, tile1 -> buf1 (tile1: ct=1 -> +32)
  GB0(0, 0); GB1(0, 0); GA(0, 0, 0); GA(1, 0, 0);
  GB0(32, 32768); GB1(32, 32768); GA(0, 32, 32768); GA(1, 32, 32768);
  asm volatile("s_waitcnt vmcnt(4)" ::: "memory");  // tile0 complete
  __builtin_amdgcn_s_barrier();

  int cbo = 0, sbo = 65536;    // consume buf, stage buf (ring-3 byte offsets)
  int tap2 = 0, ct2 = 2;       // indices of tile q+2
  int oA2 = 64, oB2 = 64;

#pragma unroll 1
  for (int q = 0; q < 36; ++q) {
    char* cb = ldsc + cbo;
    // ---------- phase 0: B frags + A m0-3, stage B(t+2) ----------
    bf16x8 b0 = *(const bf16x8*)(cb + laneB);
    bf16x8 b1 = *(const bf16x8*)(cb + laneB + 1024);
    bf16x8 b2 = *(const bf16x8*)(cb + laneB + 2048);
    bf16x8 b3 = *(const bf16x8*)(cb + laneB + 3072);
    bf16x8 a0 = *(const bf16x8*)(cb + laneA);
    bf16x8 a1 = *(const bf16x8*)(cb + laneA + 1024);
    bf16x8 a2 = *(const bf16x8*)(cb + laneA + 2048);
    bf16x8 a3 = *(const bf16x8*)(cb + laneA + 3072);
    GB0(oB2, sbo);
    GB1(oB2, sbo);
    __builtin_amdgcn_s_barrier();
    asm volatile("s_waitcnt lgkmcnt(0)" ::: "memory");
    __builtin_amdgcn_sched_barrier(0);
    __builtin_amdgcn_s_setprio(1);
    acc[0][0] = MF(a0, b0, acc[0][0]);
    acc[0][1] = MF(a0, b1, acc[0][1]);
    acc[0][2] = MF(a0, b2, acc[0][2]);
    acc[0][3] = MF(a0, b3, acc[0][3]);
    acc[1][0] = MF(a1, b0, acc[1][0]);
    acc[1][1] = MF(a1, b1, acc[1][1]);
    acc[1][2] = MF(a1, b2, acc[1][2]);
    acc[1][3] = MF(a1, b3, acc[1][3]);
    acc[2][0] = MF(a2, b0, acc[2][0]);
    acc[2][1] = MF(a2, b1, acc[2][1]);
    acc[2][2] = MF(a2, b2, acc[2][2]);
    acc[2][3] = MF(a2, b3, acc[2][3]);
    acc[3][0] = MF(a3, b0, acc[3][0]);
    acc[3][1] = MF(a3, b1, acc[3][1]);
    acc[3][2] = MF(a3, b2, acc[3][2]);
    acc[3][3] = MF(a3, b3, acc[3][3]);
    __builtin_amdgcn_s_setprio(0);
    __builtin_amdgcn_s_barrier();

    // ---------- phase 1: A m4-7 (B reused), stage A(t+2) ----------
    bf16x8 a4 = *(const bf16x8*)(cb + laneA + 4096);
    bf16x8 a5 = *(const bf16x8*)(cb + laneA + 5120);
    bf16x8 a6 = *(const bf16x8*)(cb + laneA + 6144);
    bf16x8 a7 = *(const bf16x8*)(cb + laneA + 7168);
    GA(0, oA2, sbo);
    GA(1, oA2, sbo);
    __builtin_amdgcn_s_barrier();
    asm volatile("s_waitcnt lgkmcnt(0)" ::: "memory");
    __builtin_amdgcn_sched_barrier(0);
    __builtin_amdgcn_s_setprio(1);
    acc[4][0] = MF(a4, b0, acc[4][0]);
    acc[4][1] = MF(a4, b1, acc[4][1]);
    acc[4][2] = MF(a4, b2, acc[4][2]);
    acc[4][3] = MF(a4, b3, acc[4][3]);
    acc[5][0] = MF(a5, b0, acc[5][0]);
    acc[5][1] = MF(a5, b1, acc[5][1]);
    acc[5][2] = MF(a5, b2, acc[5][2]);
    acc[5][3] = MF(a5, b3, acc[5][3]);
    acc[6][0] = MF(a6, b0, acc[6][0]);
    acc[6][1] = MF(a6, b1, acc[6][1]);
    acc[6][2] = MF(a6, b2, acc[6][2]);
    acc[6][3] = MF(a6, b3, acc[6][3]);
    acc[7][0] = MF(a7, b0, acc[7][0]);
    acc[7][1] = MF(a7, b1, acc[7][1]);
    acc[7][2] = MF(a7, b2, acc[7][2]);
    acc[7][3] = MF(a7, b3, acc[7][3]);
    __builtin_amdgcn_s_setprio(0);
    // tile t+1 (staged last iter) must be complete; t+2's 4 stay in flight
    asm volatile("s_waitcnt vmcnt(4)" ::: "memory");
    __builtin_amdgcn_s_barrier();

    cbo = (cbo == 65536) ? 0 : cbo + 32768;
    sbo = (sbo == 65536) ? 0 : sbo + 32768;
    if (q < 33) {                // advance offsets to tile q+3 (<=35)
      if (ct2 == 3) {
        ct2 = 0;
        ++tap2;
        oA2 = tap2 << 15;
        int r3 = (tap2 * 43) >> 7;                      // tap2/3 for tap2<9
        oB2 = (r3 * 58 + (tap2 - r3 * 3)) << 7;
      } else {
        ++ct2;
        oA2 += 32;
        oB2 += 32;
      }
    }
  }
  asm volatile("s_waitcnt vmcnt(0)" ::: "memory");  // drain dummy stages
#undef GA
#undef GB0
#undef GB1

  // ---- epilogue: D[row=hi*4+reg][col=r15]; row->k, col->pixel
  int kb = (wr << 7) + (hi << 2);
  int pb = (pt << 8) + (wc << 6) + r15;
#pragma unroll
  for (int m = 0; m < 8; ++m) {
    int kk = kb + (m << 4);
    float4 bv = *(const float4*)(bias + kk);
#pragma unroll
    for (int n = 0; n < 4; ++n) {
      int p = pb + (n << 4);
      int ni = p / 3136;
      int hw = p - ni * 3136;
      int base = (ni * 256 + kk) * 3136 + hw;
      f32x4 v = acc[m][n];
      out[base] = v[0] + bv.x;
      out[base + 3136] = v[1] + bv.y;
      out[base + 6272] = v[2] + bv.z;
      out[base + 9408] = v[3] + bv.w;
    }
  }
}

// ---- fallback: exact fp32 direct conv (only if ws too small) -----------
__global__ void conv_naive(const float* __restrict__ x, const float* __restrict__ flt,
                           const float* __restrict__ bias, float* __restrict__ out) {
  int idx = blockIdx.x * 256 + threadIdx.x;
  if (idx >= 32 * 256 * 3136) return;
  int hw = idx % 3136;
  int k = (idx / 3136) & 255;
  int n = idx / (3136 * 256);
  int h = hw / 56, w = hw % 56;
  float acc = bias[k];
  for (int c = 0; c < 128; ++c) {
    const float* xc = x + (n * 128 + c) * 3136;
    const float* fc = flt + (k * 128 + c) * 9;
#pragma unroll
    for (int r = 0; r < 3; ++r) {
      int hh = h + r - 1;
      if ((unsigned)hh >= 56u) continue;
#pragma unroll
      for (int s = 0; s < 3; ++s) {
        int ww = w + s - 1;
        if ((unsigned)ww >= 56u) continue;
        acc += xc[hh * 56 + ww] * fc[r * 3 + s];
      }
    }
  }
  out[idx] = acc;
}

extern "C" void kernel_launch(void* const* d_in, const int* in_sizes, int n_in,
                              void* d_out, int out_size, void* d_ws, size_t ws_size,
                              hipStream_t stream) {
  const float* x = (const float*)d_in[0];
  const float* flt = (const float*)d_in[1];
  const float* bias = (const float*)d_in[2];
  float* out = (float*)d_out;

  size_t need = (size_t)XP_BYTES + (size_t)WT_ELEMS * 2;
  if (ws_size < need) {
    conv_naive<<<(32 * 256 * 3136 + 255) / 256, 256, 0, stream>>>(x, flt, bias, out);
    return;
  }

  unsigned short* xp = (unsigned short*)d_ws;
  unsigned short* wtb = (unsigned short*)((char*)d_ws + XP_BYTES);

  border_zero<<<456, 256, 0, stream>>>(xp);           // 456*256 = 116736 exactly
  prep_x<<<32 * 4 * 49, 256, 0, stream>>>(x, xp);     // 6272 blocks
  prep_w<<<WT_ELEMS / 256, 256, 0, stream>>>(flt, wtb);
  conv_mfma<<<392, 512, 0, stream>>>(xp, wtb, bias, out);
}

// Round 8
// 95.617 us; speedup vs baseline: 1.0391x; 1.0391x over previous
//
#include <hip/hip_runtime.h>
#include <hip/hip_bf16.h>
#include <cstdint>

// Conv2d 3x3 s1 p1, NCHW fp32 -> implicit GEMM on bf16 MFMA.
// x: [32][128][56][56] f32, filters: [256][128][3][3] f32, biases: [256] f32
// out: [32][256][56][56] f32
// ws: Xp (NHWC padded bf16 [32][58][58][128]) then AFrag (bf16, 576KB).
//
// R8: A direct-to-register (L2-hot, fragment-linear layout), B-only LDS.
// Block tile 128(M=k)x128(N=pix), 4 waves 2x2, per-wave 64x64 (acc 4x4).
// Ring-3 B bufs of 8KB = 24KB LDS; 3 blocks/CU (launch_bounds 256,3).
// Per tile: 4 B ds_read_b128 + 4 A global b128 (prefetch t+1, dbuf regs)
// + 2 B gload_lds (stage t+2) + 16 MFMA + vmcnt(2) + s_barrier.

typedef __bf16 bf16x8 __attribute__((ext_vector_type(8)));
typedef float f32x4 __attribute__((ext_vector_type(4)));

#define XP_ELEMS (32 * 430592)            // 58*58*128 per image
#define XP_BYTES (XP_ELEMS * 2)           // 27,557,888
#define AF_ELEMS (9 * 256 * 128)          // 294,912 (576KB bf16)

__device__ __forceinline__ unsigned short f2bf(float f) {
  __bf16 b = (__bf16)f;
  return __builtin_bit_cast(unsigned short, b);
}

__device__ __forceinline__ void gload16(const void* g, void* l) {
  __builtin_amdgcn_global_load_lds(
      (const __attribute__((address_space(1))) unsigned int*)g,
      (__attribute__((address_space(3))) unsigned int*)l,
      16, 0, 0);
}

// ---- prep: x NCHW f32 -> padded NHWC bf16 ------------------------------
__global__ __launch_bounds__(256) void prep_x(const float* __restrict__ x,
                                              unsigned short* __restrict__ xp) {
  __shared__ unsigned short lt[64][34];  // [hw][c] tile, padded stride
  int b = blockIdx.x;
  int hwt = b % 49;          // 49 tiles of 64 hw positions
  int ct  = (b / 49) & 3;    // 4 tiles of 32 channels
  int n   = b / 196;
  int t = threadIdx.x;
  int c_loc = t >> 3, col8 = t & 7;
  int hw0 = hwt << 6, c0 = ct << 5;

  const float* src = x + ((n * 128 + c0 + c_loc) * 3136 + hw0 + (col8 << 3));
  float4 v0 = *(const float4*)src;
  float4 v1 = *(const float4*)(src + 4);
  int hb = col8 << 3;
  lt[hb + 0][c_loc] = f2bf(v0.x);
  lt[hb + 1][c_loc] = f2bf(v0.y);
  lt[hb + 2][c_loc] = f2bf(v0.z);
  lt[hb + 3][c_loc] = f2bf(v0.w);
  lt[hb + 4][c_loc] = f2bf(v1.x);
  lt[hb + 5][c_loc] = f2bf(v1.y);
  lt[hb + 6][c_loc] = f2bf(v1.z);
  lt[hb + 7][c_loc] = f2bf(v1.w);
  __syncthreads();

  int hwl = t >> 2, cs = t & 3;
  const unsigned int* lr = (const unsigned int*)&lt[hwl][cs << 3];
  uint4 o = make_uint4(lr[0], lr[1], lr[2], lr[3]);
  int hw = hw0 + hwl;
  int hp = hw / 56 + 1, wp = hw % 56 + 1;
  unsigned short* dst = xp + (n * 430592 + (hp * 58 + wp) * 128 + c0 + (cs << 3));
  *(uint4*)dst = o;
}

// ---- prep: zero the padding border of Xp -------------------------------
__global__ __launch_bounds__(256) void border_zero(unsigned short* __restrict__ xp) {
  int idx = blockIdx.x * 256 + threadIdx.x;   // grid sized exactly 116736
  int img = idx / 3648;
  int j = idx - img * 3648;
  int u4off;
  if (j < 928) {
    u4off = j;                      // row hp=0
  } else if (j < 1856) {
    u4off = 52896 + (j - 928);      // row hp=57
  } else {
    int k = j - 1856;
    int hp = 1 + (k >> 5);
    int r = k & 31;
    int wp = (r < 16) ? 0 : 57;
    u4off = (hp * 58 + wp) * 16 + (r & 15);
  }
  uint4 z = make_uint4(0u, 0u, 0u, 0u);
  *((uint4*)xp + img * 53824 + u4off) = z;
}

// ---- prep: filters OIHW f32 -> AFrag[q][g][lane] bf16 ------------------
// q = tap*4 + ct (36 K-tiles of 32), g = output-row group (16 rows),
// lane l = (row r15 = l&15, kslot hi = l>>4). Element e: c = ct*32+hi*8+e.
// AFrag[((q*16+g)*64+l)*8 + e] = bf16(filters[kout=g*16+r15][c][tap]).
__global__ __launch_bounds__(256) void prep_w(const float* __restrict__ f,
                                              unsigned short* __restrict__ af) {
  int idx = blockIdx.x * 256 + threadIdx.x;   // 36864 threads exactly
  int q = idx >> 10;
  int g = (idx >> 6) & 15;
  int l = idx & 63;
  int tap = q >> 2, ct = q & 3;
  int kout = g * 16 + (l & 15);
  int c0 = ct * 32 + ((l >> 4) << 3);
  unsigned short v[8];
#pragma unroll
  for (int e = 0; e < 8; ++e)
    v[e] = f2bf(f[(kout * 128 + c0 + e) * 9 + tap]);
  *(uint4*)(af + idx * 8) = *(const uint4*)v;
}

// ---- main: implicit GEMM, 128x128 tile, A-in-reg, ring-3 B LDS ---------
#define MF(A, B, C) __builtin_amdgcn_mfma_f32_16x16x32_bf16((A), (B), (C), 0, 0, 0)

__global__ __launch_bounds__(256, 3) void conv_mfma(const unsigned short* __restrict__ xp,
                                                    const unsigned short* __restrict__ af,
                                                    const float* __restrict__ bias,
                                                    float* __restrict__ out) {
  __shared__ unsigned short ldsB[3 * 4096];  // 3 bufs x 8KB (B only)
  char* ldsc = (char*)ldsB;
  int bid = blockIdx.x;
  // XCD-aware bijective swizzle: 1568 = 8*196; both mt of a pt adjacent.
  int sw = (bid & 7) * 196 + (bid >> 3);
  int mt = sw & 1;          // 2 M-tiles (k 0..127 / 128..255)
  int pt = sw >> 1;         // 784 pixel tiles of 128
  int t = threadIdx.x;
  int wv = t >> 6, l = t & 63;
  int wr = wv >> 1, wc = wv & 1;
  int r15 = l & 15, hi = l >> 4;

  // ---- B staging map: row = t>>2 (0..63) per chunk, phys slot = t&3,
  // pre-swizzled source slot sd = slot ^ f(row), f(row)=(row>>1)&3.
  int row0 = t >> 2;
  int sd = (t & 3) ^ ((row0 >> 1) & 3);
  const unsigned short* srcB0;
  const unsigned short* srcB1;
  {
    const unsigned short* sb[2];
#pragma unroll
    for (int j = 0; j < 2; ++j) {
      int p = (pt << 7) + (j << 6) + row0;
      int ni = p / 3136, hw = p - ni * 3136;
      sb[j] = xp + (ni * 430592 + ((hw / 56) * 58 + (hw % 56)) * 128 + sd * 8);
    }
    srcB0 = sb[0]; srcB1 = sb[1];
  }
  int stW = wv << 10;  // wave's 1KB chunk per 4KB region

#define GB0(oB, bufb) gload16(srcB0 + (oB), ldsc + (bufb) + stW)
#define GB1(oB, bufb) gload16(srcB1 + (oB), ldsc + (bufb) + 4096 + stW)

  // ---- A direct: lane pointer into AFrag. Wave (mt,wr) uses g0 = mt*8+wr*4.
  const unsigned short* srcA = af + (mt * 8 + wr * 4) * 512 + l * 8;
  // per tile q, frag m: srcA + q*8192 + m*512 (elements)

  // ---- B fragment read offsets: data slot hi of row r -> phys hi^((r15>>1)&3)
  int xr = (r15 >> 1) & 3;
  int boff = ((wc << 6) + r15) * 64 + ((hi ^ xr) << 4);   // + n*1024 (bytes)

  f32x4 acc[4][4];
#pragma unroll
  for (int m = 0; m < 4; ++m)
#pragma unroll
    for (int n = 0; n < 4; ++n) acc[m][n] = (f32x4){0.f, 0.f, 0.f, 0.f};

  bf16x8 aC[4], aN[4];
#pragma unroll
  for (int m = 0; m < 4; ++m) aC[m] = *(const bf16x8*)(srcA + m * 512);
  __builtin_amdgcn_sched_barrier(0);   // A loads issue before B stages
  // tile q: tap=q>>2, ct=q&3; oB = ((tap/3)*58+tap%3)*128 + ct*32 (elems)
  GB0(0, 0); GB1(0, 0);                // tile 0 -> buf 0
  GB0(32, 8192); GB1(32, 8192);        // tile 1 -> buf 1
  asm volatile("s_waitcnt vmcnt(2)" ::: "memory");  // A(0)+B(0) done
  __builtin_amdgcn_s_barrier();

  int cbo = 0, sbo = 16384;    // consume buf, stage buf (ring-3 byte offsets)
  int tap2 = 0, ct2 = 2;       // indices of tile q+2
  int oB2 = 64;

#pragma unroll 2
  for (int q = 0; q < 36; ++q) {
    char* cb = ldsc + cbo;
    bf16x8 bb[4];
#pragma unroll
    for (int n = 0; n < 4; ++n)
      bb[n] = *(const bf16x8*)(cb + boff + (n << 10));
    int qn = (q < 35) ? q + 1 : 35;                 // clamp tail
    const unsigned short* pA = srcA + qn * 8192;
#pragma unroll
    for (int m = 0; m < 4; ++m) aN[m] = *(const bf16x8*)(pA + m * 512);
    __builtin_amdgcn_sched_barrier(0);   // pin: A(t+1) issued before B(t+2)
    GB0(oB2, sbo);
    GB1(oB2, sbo);
#pragma unroll
    for (int m = 0; m < 4; ++m)
#pragma unroll
      for (int n = 0; n < 4; ++n)
        acc[m][n] = MF(aC[m], bb[n], acc[m][n]);
    // queue: B(t+1)x2 [t-1], A(t+1)x4 [t], B(t+2)x2 [t] -> wait all but 2:
    asm volatile("s_waitcnt vmcnt(2)" ::: "memory");
    __builtin_amdgcn_s_barrier();
#pragma unroll
    for (int m = 0; m < 4; ++m) aC[m] = aN[m];
    cbo = (cbo == 16384) ? 0 : cbo + 8192;
    sbo = (sbo == 16384) ? 0 : sbo + 8192;
    if (q < 33) {                // advance oB2 to tile q+3 (<=35)
      if (ct2 == 3) {
        ct2 = 0;
        ++tap2;
        int r3 = (tap2 * 43) >> 7;                  // tap2/3 for tap2<9
        oB2 = (r3 * 58 + (tap2 - r3 * 3)) << 7;
      } else {
        ++ct2;
        oB2 += 32;
      }
    }
  }
  asm volatile("s_waitcnt vmcnt(0)" ::: "memory");  // drain dummy stages
#undef GB0
#undef GB1

  // ---- epilogue: D[row=hi*4+reg][col=r15]; row->k, col->pixel
  int kb = mt * 128 + (wr << 6) + (hi << 2);
  int pb = (pt << 7) + (wc << 6) + r15;
#pragma unroll
  for (int m = 0; m < 4; ++m) {
    int kk = kb + (m << 4);
    float4 bv = *(const float4*)(bias + kk);
#pragma unroll
    for (int n = 0; n < 4; ++n) {
      int p = pb + (n << 4);
      int ni = p / 3136;
      int hw = p - ni * 3136;
      int base = (ni * 256 + kk) * 3136 + hw;
      f32x4 v = acc[m][n];
      out[base] = v[0] + bv.x;
      out[base + 3136] = v[1] + bv.y;
      out[base + 6272] = v[2] + bv.z;
      out[base + 9408] = v[3] + bv.w;
    }
  }
}

// ---- fallback: exact fp32 direct conv (only if ws too small) -----------
__global__ void conv_naive(const float* __restrict__ x, const float* __restrict__ flt,
                           const float* __restrict__ bias, float* __restrict__ out) {
  int idx = blockIdx.x * 256 + threadIdx.x;
  if (idx >= 32 * 256 * 3136) return;
  int hw = idx % 3136;
  int k = (idx / 3136) & 255;
  int n = idx / (3136 * 256);
  int h = hw / 56, w = hw % 56;
  float acc = bias[k];
  for (int c = 0; c < 128; ++c) {
    const float* xc = x + (n * 128 + c) * 3136;
    const float* fc = flt + (k * 128 + c) * 9;
#pragma unroll
    for (int r = 0; r < 3; ++r) {
      int hh = h + r - 1;
      if ((unsigned)hh >= 56u) continue;
#pragma unroll
      for (int s = 0; s < 3; ++s) {
        int ww = w + s - 1;
        if ((unsigned)ww >= 56u) continue;
        acc += xc[hh * 56 + ww] * fc[r * 3 + s];
      }
    }
  }
  out[idx] = acc;
}

extern "C" void kernel_launch(void* const* d_in, const int* in_sizes, int n_in,
                              void* d_out, int out_size, void* d_ws, size_t ws_size,
                              hipStream_t stream) {
  const float* x = (const float*)d_in[0];
  const float* flt = (const float*)d_in[1];
  const float* bias = (const float*)d_in[2];
  float* out = (float*)d_out;

  size_t need = (size_t)XP_BYTES + (size_t)AF_ELEMS * 2;
  if (ws_size < need) {
    conv_naive<<<(32 * 256 * 3136 + 255) / 256, 256, 0, stream>>>(x, flt, bias, out);
    return;
  }

  unsigned short* xp = (unsigned short*)d_ws;
  unsigned short* afrag = (unsigned short*)((char*)d_ws + XP_BYTES);

  border_zero<<<456, 256, 0, stream>>>(xp);           // 456*256 = 116736 exactly
  prep_x<<<32 * 4 * 49, 256, 0, stream>>>(x, xp);     // 6272 blocks
  prep_w<<<144, 256, 0, stream>>>(flt, afrag);        // 36864 threads exactly
  conv_mfma<<<1568, 256, 0, stream>>>(xp, afrag, bias, out);
}

// Round 9
// 90.003 us; speedup vs baseline: 1.1039x; 1.0624x over previous
//
#include <hip/hip_runtime.h>
#include <hip/hip_bf16.h>
#include <cstdint>

// Conv2d 3x3 s1 p1, NCHW fp32 -> implicit GEMM on bf16 MFMA.
// x: [32][128][56][56] f32, filters: [256][128][3][3] f32, biases: [256] f32
// out: [32][256][56][56] f32
// ws: Xp (NHWC padded bf16 [32][58][58][128]) then AFrag (bf16, 576KB).
//
// R9 = R8 + 4 blocks/CU (launch_bounds(256,4); 128 unified regs fits
// 4 waves/SIMD exactly) + single fused prep kernel (3 launches -> 2).
// Main: block tile 128(M=k)x128(N=pix), 4 waves 2x2, per-wave 64x64.
// A (filters) direct-to-VGPR from L2-hot fragment-linear AFrag, dbuf.
// B via ring-3 LDS bufs (8KB each), prefetch distance 2, vmcnt(2)/tile.

typedef __bf16 bf16x8 __attribute__((ext_vector_type(8)));
typedef float f32x4 __attribute__((ext_vector_type(4)));

#define XP_ELEMS (32 * 430592)            // 58*58*128 per image
#define XP_BYTES (XP_ELEMS * 2)           // 27,557,888
#define AF_ELEMS (9 * 256 * 128)          // 294,912 (576KB bf16)

__device__ __forceinline__ unsigned short f2bf(float f) {
  __bf16 b = (__bf16)f;
  return __builtin_bit_cast(unsigned short, b);
}

__device__ __forceinline__ void gload16(const void* g, void* l) {
  __builtin_amdgcn_global_load_lds(
      (const __attribute__((address_space(1))) unsigned int*)g,
      (__attribute__((address_space(3))) unsigned int*)l,
      16, 0, 0);
}

// ---- fused prep: x->Xp (NHWC padded bf16), border zero, filters->AFrag --
// blocks [0,6272): x transpose-convert; [6272,6728): border zero;
// [6728,6872): filter fragment layout. All writes disjoint.
__global__ __launch_bounds__(256) void prep_all(const float* __restrict__ x,
                                                const float* __restrict__ f,
                                                unsigned short* __restrict__ xp,
                                                unsigned short* __restrict__ af) {
  int b = blockIdx.x;
  int t = threadIdx.x;
  if (b < 6272) {
    // ---- prep_x: NCHW f32 -> padded NHWC bf16, 64hw x 32c tile ----
    __shared__ unsigned short lt[64][34];
    int hwt = b % 49;
    int ct  = (b / 49) & 3;
    int n   = b / 196;
    int c_loc = t >> 3, col8 = t & 7;
    int hw0 = hwt << 6, c0 = ct << 5;

    const float* src = x + ((n * 128 + c0 + c_loc) * 3136 + hw0 + (col8 << 3));
    float4 v0 = *(const float4*)src;
    float4 v1 = *(const float4*)(src + 4);
    int hb = col8 << 3;
    lt[hb + 0][c_loc] = f2bf(v0.x);
    lt[hb + 1][c_loc] = f2bf(v0.y);
    lt[hb + 2][c_loc] = f2bf(v0.z);
    lt[hb + 3][c_loc] = f2bf(v0.w);
    lt[hb + 4][c_loc] = f2bf(v1.x);
    lt[hb + 5][c_loc] = f2bf(v1.y);
    lt[hb + 6][c_loc] = f2bf(v1.z);
    lt[hb + 7][c_loc] = f2bf(v1.w);
    __syncthreads();

    int hwl = t >> 2, cs = t & 3;
    const unsigned int* lr = (const unsigned int*)&lt[hwl][cs << 3];
    uint4 o = make_uint4(lr[0], lr[1], lr[2], lr[3]);
    int hw = hw0 + hwl;
    int hp = hw / 56 + 1, wp = hw % 56 + 1;
    unsigned short* dst = xp + (n * 430592 + (hp * 58 + wp) * 128 + c0 + (cs << 3));
    *(uint4*)dst = o;
  } else if (b < 6728) {
    // ---- border zero: 116736 uint4 ----
    int idx = (b - 6272) * 256 + t;
    int img = idx / 3648;
    int j = idx - img * 3648;
    int u4off;
    if (j < 928) {
      u4off = j;                      // row hp=0
    } else if (j < 1856) {
      u4off = 52896 + (j - 928);      // row hp=57
    } else {
      int k = j - 1856;
      int hp = 1 + (k >> 5);
      int r = k & 31;
      int wp = (r < 16) ? 0 : 57;
      u4off = (hp * 58 + wp) * 16 + (r & 15);
    }
    uint4 z = make_uint4(0u, 0u, 0u, 0u);
    *((uint4*)xp + img * 53824 + u4off) = z;
  } else {
    // ---- prep_w: OIHW f32 -> AFrag[q][g][lane][8] bf16 ----
    // q = tap*4+ct, g = 16-row group, lane l=(r15,hi). c = ct*32+hi*8+e.
    int idx = (b - 6728) * 256 + t;     // < 36864
    int q = idx >> 10;
    int g = (idx >> 6) & 15;
    int l = idx & 63;
    int tap = q >> 2, ct = q & 3;
    int kout = g * 16 + (l & 15);
    int c0 = ct * 32 + ((l >> 4) << 3);
    unsigned short v[8];
#pragma unroll
    for (int e = 0; e < 8; ++e)
      v[e] = f2bf(f[(kout * 128 + c0 + e) * 9 + tap]);
    *(uint4*)(af + idx * 8) = *(const uint4*)v;
  }
}

// ---- main: implicit GEMM, 128x128 tile, A-in-reg, ring-3 B LDS ---------
#define MF(A, B, C) __builtin_amdgcn_mfma_f32_16x16x32_bf16((A), (B), (C), 0, 0, 0)

__global__ __launch_bounds__(256, 4) void conv_mfma(const unsigned short* __restrict__ xp,
                                                    const unsigned short* __restrict__ af,
                                                    const float* __restrict__ bias,
                                                    float* __restrict__ out) {
  __shared__ unsigned short ldsB[3 * 4096];  // 3 bufs x 8KB (B only)
  char* ldsc = (char*)ldsB;
  int bid = blockIdx.x;
  // XCD-aware bijective swizzle: 1568 = 8*196; both mt of a pt adjacent.
  int sw = (bid & 7) * 196 + (bid >> 3);
  int mt = sw & 1;          // 2 M-tiles (k 0..127 / 128..255)
  int pt = sw >> 1;         // 784 pixel tiles of 128
  int t = threadIdx.x;
  int wv = t >> 6, l = t & 63;
  int wr = wv >> 1, wc = wv & 1;
  int r15 = l & 15, hi = l >> 4;

  // ---- B staging map: row = t>>2 (0..63) per chunk, phys slot = t&3,
  // pre-swizzled source slot sd = slot ^ f(row), f(row)=(row>>1)&3.
  int row0 = t >> 2;
  int sd = (t & 3) ^ ((row0 >> 1) & 3);
  const unsigned short* srcB0;
  const unsigned short* srcB1;
  {
    const unsigned short* sb[2];
#pragma unroll
    for (int j = 0; j < 2; ++j) {
      int p = (pt << 7) + (j << 6) + row0;
      int ni = p / 3136, hw = p - ni * 3136;
      sb[j] = xp + (ni * 430592 + ((hw / 56) * 58 + (hw % 56)) * 128 + sd * 8);
    }
    srcB0 = sb[0]; srcB1 = sb[1];
  }
  int stW = wv << 10;  // wave's 1KB chunk per 4KB region

#define GB0(oB, bufb) gload16(srcB0 + (oB), ldsc + (bufb) + stW)
#define GB1(oB, bufb) gload16(srcB1 + (oB), ldsc + (bufb) + 4096 + stW)

  // ---- A direct: lane pointer into AFrag. Wave (mt,wr) uses g0 = mt*8+wr*4.
  const unsigned short* srcA = af + (mt * 8 + wr * 4) * 512 + l * 8;
  // per tile q, frag m: srcA + q*8192 + m*512 (elements)

  // ---- B fragment read offsets: data slot hi of row r -> phys hi^((r15>>1)&3)
  int xr = (r15 >> 1) & 3;
  int boff = ((wc << 6) + r15) * 64 + ((hi ^ xr) << 4);   // + n*1024 (bytes)

  f32x4 acc[4][4];
#pragma unroll
  for (int m = 0; m < 4; ++m)
#pragma unroll
    for (int n = 0; n < 4; ++n) acc[m][n] = (f32x4){0.f, 0.f, 0.f, 0.f};

  bf16x8 aC[4], aN[4];
#pragma unroll
  for (int m = 0; m < 4; ++m) aC[m] = *(const bf16x8*)(srcA + m * 512);
  __builtin_amdgcn_sched_barrier(0);   // A loads issue before B stages
  // tile q: tap=q>>2, ct=q&3; oB = ((tap/3)*58+tap%3)*128 + ct*32 (elems)
  GB0(0, 0); GB1(0, 0);                // tile 0 -> buf 0
  GB0(32, 8192); GB1(32, 8192);        // tile 1 -> buf 1
  asm volatile("s_waitcnt vmcnt(2)" ::: "memory");  // A(0)+B(0) done
  __builtin_amdgcn_s_barrier();

  int cbo = 0, sbo = 16384;    // consume buf, stage buf (ring-3 byte offsets)
  int tap2 = 0, ct2 = 2;       // indices of tile q+2
  int oB2 = 64;

#pragma unroll 2
  for (int q = 0; q < 36; ++q) {
    char* cb = ldsc + cbo;
    bf16x8 bb[4];
#pragma unroll
    for (int n = 0; n < 4; ++n)
      bb[n] = *(const bf16x8*)(cb + boff + (n << 10));
    int qn = (q < 35) ? q + 1 : 35;                 // clamp tail
    const unsigned short* pA = srcA + qn * 8192;
#pragma unroll
    for (int m = 0; m < 4; ++m) aN[m] = *(const bf16x8*)(pA + m * 512);
    __builtin_amdgcn_sched_barrier(0);   // pin: A(t+1) issued before B(t+2)
    GB0(oB2, sbo);
    GB1(oB2, sbo);
#pragma unroll
    for (int m = 0; m < 4; ++m)
#pragma unroll
      for (int n = 0; n < 4; ++n)
        acc[m][n] = MF(aC[m], bb[n], acc[m][n]);
    // queue: B(t+1)x2 [t-1], A(t+1)x4 [t], B(t+2)x2 [t] -> wait all but 2:
    asm volatile("s_waitcnt vmcnt(2)" ::: "memory");
    __builtin_amdgcn_s_barrier();
#pragma unroll
    for (int m = 0; m < 4; ++m) aC[m] = aN[m];
    cbo = (cbo == 16384) ? 0 : cbo + 8192;
    sbo = (sbo == 16384) ? 0 : sbo + 8192;
    if (q < 33) {                // advance oB2 to tile q+3 (<=35)
      if (ct2 == 3) {
        ct2 = 0;
        ++tap2;
        int r3 = (tap2 * 43) >> 7;                  // tap2/3 for tap2<9
        oB2 = (r3 * 58 + (tap2 - r3 * 3)) << 7;
      } else {
        ++ct2;
        oB2 += 32;
      }
    }
  }
  asm volatile("s_waitcnt vmcnt(0)" ::: "memory");  // drain dummy stages
#undef GB0
#undef GB1

  // ---- epilogue: D[row=hi*4+reg][col=r15]; row->k, col->pixel
  int kb = mt * 128 + (wr << 6) + (hi << 2);
  int pb = (pt << 7) + (wc << 6) + r15;
#pragma unroll
  for (int m = 0; m < 4; ++m) {
    int kk = kb + (m << 4);
    float4 bv = *(const float4*)(bias + kk);
#pragma unroll
    for (int n = 0; n < 4; ++n) {
      int p = pb + (n << 4);
      int ni = p / 3136;
      int hw = p - ni * 3136;
      int base = (ni * 256 + kk) * 3136 + hw;
      f32x4 v = acc[m][n];
      out[base] = v[0] + bv.x;
      out[base + 3136] = v[1] + bv.y;
      out[base + 6272] = v[2] + bv.z;
      out[base + 9408] = v[3] + bv.w;
    }
  }
}

// ---- fallback: exact fp32 direct conv (only if ws too small) -----------
__global__ void conv_naive(const float* __restrict__ x, const float* __restrict__ flt,
                           const float* __restrict__ bias, float* __restrict__ out) {
  int idx = blockIdx.x * 256 + threadIdx.x;
  if (idx >= 32 * 256 * 3136) return;
  int hw = idx % 3136;
  int k = (idx / 3136) & 255;
  int n = idx / (3136 * 256);
  int h = hw / 56, w = hw % 56;
  float acc = bias[k];
  for (int c = 0; c < 128; ++c) {
    const float* xc = x + (n * 128 + c) * 3136;
    const float* fc = flt + (k * 128 + c) * 9;
#pragma unroll
    for (int r = 0; r < 3; ++r) {
      int hh = h + r - 1;
      if ((unsigned)hh >= 56u) continue;
#pragma unroll
      for (int s = 0; s < 3; ++s) {
        int ww = w + s - 1;
        if ((unsigned)ww >= 56u) continue;
        acc += xc[hh * 56 + ww] * fc[r * 3 + s];
      }
    }
  }
  out[idx] = acc;
}

extern "C" void kernel_launch(void* const* d_in, const int* in_sizes, int n_in,
                              void* d_out, int out_size, void* d_ws, size_t ws_size,
                              hipStream_t stream) {
  const float* x = (const float*)d_in[0];
  const float* flt = (const float*)d_in[1];
  const float* bias = (const float*)d_in[2];
  float* out = (float*)d_out;

  size_t need = (size_t)XP_BYTES + (size_t)AF_ELEMS * 2;
  if (ws_size < need) {
    conv_naive<<<(32 * 256 * 3136 + 255) / 256, 256, 0, stream>>>(x, flt, bias, out);
    return;
  }

  unsigned short* xp = (unsigned short*)d_ws;
  unsigned short* afrag = (unsigned short*)((char*)d_ws + XP_BYTES);

  prep_all<<<6872, 256, 0, stream>>>(x, flt, xp, afrag);
  conv_mfma<<<1568, 256, 0, stream>>>(xp, afrag, bias, out);
}